// Round 2
// baseline (145.722 us; speedup 1.0000x reference)
//
#include <hip/hip_runtime.h>

// TorchVQC: 8-qubit statevector, B=16384, D=256, fp32 complex.
// R2 layout: 4 batch elements per wave (16 lanes each), 16 amplitudes per lane.
// Stored index s = (j<<4) | lane16 : lane16 = s[3:0], register j = s[7:4].
// Qubit k <-> true bit p = 7-k. CNOTs are folded away via GF(2) relabeling:
// true = A * stored. Gate on true bit p pairs s <-> s^v (v = A^{-1} e_p) with
// "hi" indicator parity(A_p & s). A/v/u tables precomputed below (verified
// A.v = e_p, u.v = 1 for every gate).
//
//   after layer-0 CNOT ring (ctrl k -> tgt k+1):
//     A = [0xFF,0xFE,0xFC,0xF8,0xF0,0xE0,0xC0,0x7F]  (rows 0..7)
//     v(p=0..7) = [0xC1,0x03,0x06,0x0C,0x18,0x30,0x60,0xC0]
//   after layer-1 CNOT ring (ctrl k -> tgt k+2):
//     A = [0x33,0x99,0xCC,0x67,0x30,0x9F,0xF3,0xE6]   (readout signs)

__device__ __forceinline__ void cmul(float& ar, float& ai, float br, float bi) {
    const float r = ar * br - ai * bi;
    const float i = ar * bi + ai * br;
    ar = r; ai = i;
}

// Generic 1q gate under relabeling. VREG/VLANE: register/lane part of toggle v.
// UREG/ULANE: register/lane part of sign row u. hi(s) = par(lane&ULANE)^par(j&UREG).
// hi=0 member: new = g00*own + g01*partner ; hi=1: new = g11*own + g10*partner.
template<int VREG, int VLANE, int UREG, int ULANE>
__device__ __forceinline__ void gate16(float (&sr)[16], float (&si)[16], int lane16,
    float g00r, float g00i, float g01r, float g01i,
    float g10r, float g10i, float g11r, float g11i)
{
    // orientation-selected coefficients: index 0 = (par(j&UREG)==0) member
    float a0r, a0i, b0r, b0i, a1r, a1i, b1r, b1i;
    if constexpr (ULANE != 0) {
        const bool lp = (__popc(lane16 & ULANE) & 1) != 0;
        a0r = lp ? g11r : g00r;  a0i = lp ? g11i : g00i;
        b0r = lp ? g10r : g01r;  b0i = lp ? g10i : g01i;
        a1r = lp ? g00r : g11r;  a1i = lp ? g00i : g11i;
        b1r = lp ? g01r : g10r;  b1i = lp ? g01i : g10i;
    } else {
        a0r = g00r; a0i = g00i; b0r = g01r; b0i = g01i;
        a1r = g11r; a1i = g11i; b1r = g10r; b1i = g10i;
    }
    constexpr bool flip = (__builtin_popcount(VREG & UREG) & 1) != 0;
    if constexpr (VLANE == 0) {
        // pure register pairing j <-> j^VREG
        constexpr int pivot = VREG & (-VREG);
        #pragma unroll
        for (int j = 0; j < 16; ++j) {
            if ((j & pivot) != 0) continue;
            const int j2 = j ^ VREG;
            const bool cJ = (__builtin_popcount(j & UREG) & 1) != 0;
            const bool cK = cJ ^ flip;
            const float xr = sr[j],  xi = si[j];
            const float yr = sr[j2], yi = si[j2];
            const float Ar = cJ ? a1r : a0r, Ai = cJ ? a1i : a0i;
            const float Br = cJ ? b1r : b0r, Bi = cJ ? b1i : b0i;
            const float Cr = cK ? a1r : a0r, Ci = cK ? a1i : a0i;
            const float Dr = cK ? b1r : b0r, Di = cK ? b1i : b0i;
            sr[j]  = Ar*xr - Ai*xi + Br*yr - Bi*yi;
            si[j]  = Ar*xi + Ai*xr + Br*yi + Bi*yr;
            sr[j2] = Cr*yr - Ci*yi + Dr*xr - Di*xi;
            si[j2] = Cr*yi + Ci*yr + Dr*xi + Di*xr;
        }
    } else if constexpr (VREG == 0) {
        // pure lane pairing: partner = shfl(own reg, lane^VLANE)
        #pragma unroll
        for (int j = 0; j < 16; ++j) {
            const float pr = __shfl_xor(sr[j], VLANE, 64);
            const float pi = __shfl_xor(si[j], VLANE, 64);
            const bool cJ = (__builtin_popcount(j & UREG) & 1) != 0;
            const float Ar = cJ ? a1r : a0r, Ai = cJ ? a1i : a0i;
            const float Br = cJ ? b1r : b0r, Bi = cJ ? b1i : b0i;
            const float xr = sr[j], xi = si[j];
            sr[j] = Ar*xr - Ai*xi + Br*pr - Bi*pi;
            si[j] = Ar*xi + Ai*xr + Br*pi + Bi*pr;
        }
    } else {
        // mixed: partner = shfl(sr[j^VREG], lane^VLANE); process register pairs
        constexpr int pivot = VREG & (-VREG);
        #pragma unroll
        for (int j = 0; j < 16; ++j) {
            if ((j & pivot) != 0) continue;
            const int j2 = j ^ VREG;
            const float p1r = __shfl_xor(sr[j2], VLANE, 64);
            const float p1i = __shfl_xor(si[j2], VLANE, 64);
            const float p2r = __shfl_xor(sr[j],  VLANE, 64);
            const float p2i = __shfl_xor(si[j],  VLANE, 64);
            const bool cJ = (__builtin_popcount(j & UREG) & 1) != 0;
            const bool cK = cJ ^ flip;
            const float xr = sr[j],  xi = si[j];
            const float yr = sr[j2], yi = si[j2];
            const float Ar = cJ ? a1r : a0r, Ai = cJ ? a1i : a0i;
            const float Br = cJ ? b1r : b0r, Bi = cJ ? b1i : b0i;
            const float Cr = cK ? a1r : a0r, Ci = cK ? a1i : a0i;
            const float Dr = cK ? b1r : b0r, Di = cK ? b1i : b0i;
            sr[j]  = Ar*xr - Ai*xi + Br*p1r - Bi*p1i;
            si[j]  = Ar*xi + Ai*xr + Br*p1i + Bi*p1r;
            sr[j2] = Cr*yr - Ci*yi + Dr*p2r - Di*p2i;
            si[j2] = Cr*yi + Ci*yr + Dr*p2i + Di*p2r;
        }
    }
}

// Rot = RZ(om)RY(th)RZ(ph): g00=c e^{-i(ph+om)/2}, g01=-s e^{+i(ph-om)/2},
// g10=s e^{-i(ph-om)/2}, g11=c e^{+i(ph+om)/2}   (w is wave-uniform -> s_loads)
#define ROT(L, K, VR, VL, UR, UL) do {                                  \
    const float wph = w[((L)*8 + (K))*3 + 0];                           \
    const float wth = w[((L)*8 + (K))*3 + 1];                           \
    const float wom = w[((L)*8 + (K))*3 + 2];                           \
    float c_, s_, ca_, sa_, cb_, sb_;                                   \
    __sincosf(wth * 0.5f, &s_, &c_);                                    \
    __sincosf(0.5f * (wph + wom), &sa_, &ca_);                          \
    __sincosf(0.5f * (wph - wom), &sb_, &cb_);                          \
    gate16<VR, VL, UR, UL>(sr, si, lane16,                              \
        c_*ca_, -c_*sa_,  -s_*cb_, -s_*sb_,                             \
        s_*cb_, -s_*sb_,   c_*ca_,  c_*sa_);                            \
} while (0)

// fused RZ(phi*0.5)*RY(theta*0.5) re-encoding (quarter-angle sincos)
#define RENC(K, VR, VL, UR, UL) do {                                    \
    float c_, s_, cp_, sp_;                                             \
    __sincosf(th[K] * 0.25f, &s_, &c_);                                 \
    __sincosf(ph[K] * 0.25f, &sp_, &cp_);                               \
    gate16<VR, VL, UR, UL>(sr, si, lane16,                              \
        c_*cp_, -c_*sp_,  -s_*cp_,  s_*sp_,                             \
        s_*cp_,  s_*sp_,   c_*cp_,  c_*sp_);                            \
} while (0)

__global__ __launch_bounds__(256, 4) void vqc_kernel(
    const float* __restrict__ theta,   // [B,8]
    const float* __restrict__ phi,     // [B,8]
    const float* __restrict__ jup,     // [B,28]
    const float* __restrict__ w,       // [2,8,3]
    float* __restrict__ out,           // [B,8]
    int Btot)
{
    const int wid    = (blockIdx.x * blockDim.x + threadIdx.x) >> 6;
    const int lane   = threadIdx.x & 63;
    const int lane16 = lane & 15;
    const int bq     = wid * 4 + (lane >> 4);
    const int b      = bq < Btot ? bq : Btot - 1;   // clamp for loads

    // ---- load per-batch angles ----
    float th[8], ph[8];
    {
        const float4* t4 = reinterpret_cast<const float4*>(theta + (size_t)b * 8);
        const float4* p4 = reinterpret_cast<const float4*>(phi   + (size_t)b * 8);
        const float4 a = t4[0], c = t4[1], d = p4[0], e = p4[1];
        th[0]=a.x; th[1]=a.y; th[2]=a.z; th[3]=a.w;
        th[4]=c.x; th[5]=c.y; th[6]=c.z; th[7]=c.w;
        ph[0]=d.x; ph[1]=d.y; ph[2]=d.z; ph[3]=d.w;
        ph[4]=e.x; ph[5]=e.y; ph[6]=e.z; ph[7]=e.w;
    }

    // ---- encoding column-0 entries: E0=(c*cp,-c*sp), E1=(s*cp,s*sp) ----
    float e0r[8], e0i[8], e1r[8], e1i[8];
    #pragma unroll
    for (int k = 0; k < 8; ++k) {
        float s_, c_, sp_, cp_;
        __sincosf(th[k] * 0.5f, &s_, &c_);
        __sincosf(ph[k] * 0.5f, &sp_, &cp_);
        e0r[k] = c_ * cp_;  e0i[k] = -c_ * sp_;
        e1r[k] = s_ * cp_;  e1i[k] =  s_ * sp_;
    }

    // lane-part product over qubits 4..7 (lane bits 3..0)
    float Pr, Pi;
    {
        const bool q4 = (lane16 & 8) != 0;
        Pr = q4 ? e1r[4] : e0r[4];  Pi = q4 ? e1i[4] : e0i[4];
        const bool q5 = (lane16 & 4) != 0;
        cmul(Pr, Pi, q5 ? e1r[5] : e0r[5], q5 ? e1i[5] : e0i[5]);
        const bool q6 = (lane16 & 2) != 0;
        cmul(Pr, Pi, q6 ? e1r[6] : e0r[6], q6 ? e1i[6] : e0i[6]);
        const bool q7 = (lane16 & 1) != 0;
        cmul(Pr, Pi, q7 ? e1r[7] : e0r[7], q7 ? e1i[7] : e0i[7]);
    }
    // register-part partial products: m01[a] over (q0,q1), m23[a] over (q2,q3)
    float m01r[4], m01i[4], m23r[4], m23i[4];
    #pragma unroll
    for (int a = 0; a < 4; ++a) {
        const bool hA = (a & 2) != 0, hB = (a & 1) != 0;
        float r = hA ? e1r[0] : e0r[0], i = hA ? e1i[0] : e0i[0];
        cmul(r, i, hB ? e1r[1] : e0r[1], hB ? e1i[1] : e0i[1]);
        m01r[a] = r; m01i[a] = i;
        float r2 = hA ? e1r[2] : e0r[2], i2 = hA ? e1i[2] : e0i[2];
        cmul(r2, i2, hB ? e1r[3] : e0r[3], hB ? e1i[3] : e0i[3]);
        m23r[a] = r2; m23i[a] = i2;
    }

    // ---- IsingZZ decomposition (A = I here) ----
    float J[28];
    {
        const float4* J4 = reinterpret_cast<const float4*>(jup + (size_t)b * 28);
        #pragma unroll
        for (int q = 0; q < 7; ++q) {
            const float4 x = J4[q];
            J[q*4+0]=x.x; J[q*4+1]=x.y; J[q*4+2]=x.z; J[q*4+3]=x.w;
        }
    }
    const float z4 = (lane16 & 8) ? -1.f : 1.f;
    const float z5 = (lane16 & 4) ? -1.f : 1.f;
    const float z6 = (lane16 & 2) ? -1.f : 1.f;
    const float z7 = (lane16 & 1) ? -1.f : 1.f;
    const float Q0 = J[3]*z4  + J[4]*z5  + J[5]*z6  + J[6]*z7;
    const float Q1 = J[9]*z4  + J[10]*z5 + J[11]*z6 + J[12]*z7;
    const float Q2 = J[14]*z4 + J[15]*z5 + J[16]*z6 + J[17]*z7;
    const float Q3 = J[18]*z4 + J[19]*z5 + J[20]*z6 + J[21]*z7;
    const float LL = J[22]*(z4*z5) + J[23]*(z4*z6) + J[24]*(z4*z7)
                   + J[25]*(z5*z6) + J[26]*(z5*z7) + J[27]*(z6*z7);
    const float c01 = J[0], c02 = J[1], c03 = J[2];
    const float c12 = J[7], c13 = J[8], c23 = J[13];

    // ---- init amplitudes: product state x Ising phase ----
    float sr[16], si[16];
    constexpr float HPI = 1.5707963267948966f;
    #pragma unroll
    for (int j = 0; j < 16; ++j) {
        float ur = m01r[j >> 2], ui = m01i[j >> 2];
        cmul(ur, ui, m23r[j & 3], m23i[j & 3]);
        cmul(ur, ui, Pr, Pi);
        float S = LL;
        S += ((__builtin_popcount(j & 0xC) & 1) ? -c01 : c01);
        S += ((__builtin_popcount(j & 0xA) & 1) ? -c02 : c02);
        S += ((__builtin_popcount(j & 0x9) & 1) ? -c03 : c03);
        S += ((__builtin_popcount(j & 0x6) & 1) ? -c12 : c12);
        S += ((__builtin_popcount(j & 0x5) & 1) ? -c13 : c13);
        S += ((__builtin_popcount(j & 0x3) & 1) ? -c23 : c23);
        S += ((j & 8) ? -Q0 : Q0);
        S += ((j & 4) ? -Q1 : Q1);
        S += ((j & 2) ? -Q2 : Q2);
        S += ((j & 1) ? -Q3 : Q3);
        float se, ce;
        __sincosf(-HPI * S, &se, &ce);
        sr[j] = ur * ce - ui * se;
        si[j] = ur * se + ui * ce;
    }

    // ---- layer-0 Rot gates (A = I): v = u = e_p, p = 7-k ----
    ROT(0, 0, 0x8, 0x0, 0x8, 0x0);
    ROT(0, 1, 0x4, 0x0, 0x4, 0x0);
    ROT(0, 2, 0x2, 0x0, 0x2, 0x0);
    ROT(0, 3, 0x1, 0x0, 0x1, 0x0);
    ROT(0, 4, 0x0, 0x8, 0x0, 0x8);
    ROT(0, 5, 0x0, 0x4, 0x0, 0x4);
    ROT(0, 6, 0x0, 0x2, 0x0, 0x2);
    ROT(0, 7, 0x0, 0x1, 0x0, 0x1);

    // layer-0 CNOT ring: free (relabeling). Post-ring (v,u) per qubit k:
    // k : VREG VLANE UREG ULANE
    // 0 : 0xC  0x0  0x7  0xF
    // 1 : 0x6  0x0  0xC  0x0
    // 2 : 0x3  0x0  0xE  0x0
    // 3 : 0x1  0x8  0xF  0x0
    // 4 : 0x0  0xC  0xF  0x8
    // 5 : 0x0  0x6  0xF  0xC
    // 6 : 0x0  0x3  0xF  0xE
    // 7 : 0xC  0x1  0xF  0xF

    // ---- re-encoding at half angles ----
    RENC(0, 0xC, 0x0, 0x7, 0xF);
    RENC(1, 0x6, 0x0, 0xC, 0x0);
    RENC(2, 0x3, 0x0, 0xE, 0x0);
    RENC(3, 0x1, 0x8, 0xF, 0x0);
    RENC(4, 0x0, 0xC, 0xF, 0x8);
    RENC(5, 0x0, 0x6, 0xF, 0xC);
    RENC(6, 0x0, 0x3, 0xF, 0xE);
    RENC(7, 0xC, 0x1, 0xF, 0xF);

    // ---- layer-1 Rot gates (same relabeled v/u) ----
    ROT(1, 0, 0xC, 0x0, 0x7, 0xF);
    ROT(1, 1, 0x6, 0x0, 0xC, 0x0);
    ROT(1, 2, 0x3, 0x0, 0xE, 0x0);
    ROT(1, 3, 0x1, 0x8, 0xF, 0x0);
    ROT(1, 4, 0x0, 0xC, 0xF, 0x8);
    ROT(1, 5, 0x0, 0x6, 0xF, 0xC);
    ROT(1, 6, 0x0, 0x3, 0xF, 0xE);
    ROT(1, 7, 0xC, 0x1, 0xF, 0xF);

    // layer-1 CNOT ring: free. Final A rows give readout signs:
    // k=0:A7=0xE6  k=1:A6=0xF3  k=2:A5=0x9F  k=3:A4=0x30
    // k=4:A3=0x67  k=5:A2=0xCC  k=6:A1=0x99  k=7:A0=0x33

    // ---- readout: probs, 16-point WHT over register index, lane signs ----
    float p[16];
    #pragma unroll
    for (int j = 0; j < 16; ++j) p[j] = sr[j]*sr[j] + si[j]*si[j];
    #pragma unroll
    for (int st = 1; st < 16; st <<= 1) {
        #pragma unroll
        for (int j = 0; j < 16; ++j) {
            if ((j & st) != 0) continue;
            const float a = p[j], bb = p[j | st];
            p[j] = a + bb;  p[j | st] = a - bb;
        }
    }
    float o[8];
    o[0] = (__popc(lane16 & 0x6) & 1) ? -p[0xE] : p[0xE];
    o[1] = (__popc(lane16 & 0x3) & 1) ? -p[0xF] : p[0xF];
    o[2] = (__popc(lane16 & 0xF) & 1) ? -p[0x9] : p[0x9];
    o[3] = p[0x3];                                          // lane mask 0x0
    o[4] = (__popc(lane16 & 0x7) & 1) ? -p[0x6] : p[0x6];
    o[5] = (__popc(lane16 & 0xC) & 1) ? -p[0xC] : p[0xC];
    o[6] = (__popc(lane16 & 0x9) & 1) ? -p[0x9] : p[0x9];
    o[7] = (__popc(lane16 & 0x3) & 1) ? -p[0x3] : p[0x3];

    #pragma unroll
    for (int m = 1; m <= 8; m <<= 1) {
        #pragma unroll
        for (int q = 0; q < 8; ++q) o[q] += __shfl_xor(o[q], m, 64);
    }

    if (lane16 == 0 && bq < Btot) {
        float4* op = reinterpret_cast<float4*>(out + (size_t)bq * 8);
        op[0] = make_float4(o[0], o[1], o[2], o[3]);
        op[1] = make_float4(o[4], o[5], o[6], o[7]);
    }
}

extern "C" void kernel_launch(void* const* d_in, const int* in_sizes, int n_in,
                              void* d_out, int out_size, void* d_ws, size_t ws_size,
                              hipStream_t stream) {
    const float* theta = (const float*)d_in[0];
    const float* phi   = (const float*)d_in[1];
    const float* jup   = (const float*)d_in[2];
    const float* w     = (const float*)d_in[3];
    float* out = (float*)d_out;

    const int B = in_sizes[0] / 8;              // 16384
    const int threads = 256;                    // 4 waves, 16 batch elems / block
    const int blocks = (B + 15) / 16;           // 1024 = exactly 4 blocks per CU
    hipLaunchKernelGGL(vqc_kernel, dim3(blocks), dim3(threads), 0, stream,
                       theta, phi, jup, w, out, B);
}

// Round 3
// 109.439 us; speedup vs baseline: 1.3315x; 1.3315x over previous
//
#include <hip/hip_runtime.h>

// TorchVQC: 8-qubit statevector, B=16384, D=256, fp32 complex.
// Layout: 4 batch elements per wave (16 lanes each), 16 amplitudes per lane.
// Stored index s = (j<<4) | lane16 : lane16 = s[3:0], register j = s[7:4].
// Qubit k <-> true bit p = 7-k. CNOTs folded away via GF(2) relabeling
// (true = A * stored); v/u tables verified in R2 (passed, absmax 1.95e-3).
// R3: spill fix — launch_bounds(256,2), scoped temporaries, Rot matrices
// precomputed by a 1-block prep kernel into d_ws (wave-uniform s_loads).

__device__ __forceinline__ void cmul(float& ar, float& ai, float br, float bi) {
    const float r = ar * br - ai * bi;
    const float i = ar * bi + ai * br;
    ar = r; ai = i;
}

// selected encoding-column entry: hi ? (s*cp, s*sp) : (c*cp, -c*sp)
__device__ __forceinline__ void enc_sel(float t, float p, bool hi, float& er, float& ei) {
    float s_, c_, sp_, cp_;
    __sincosf(t * 0.5f, &s_, &c_);
    __sincosf(p * 0.5f, &sp_, &cp_);
    const float m = hi ? s_ : c_;
    er = m * cp_;
    ei = hi ? m * sp_ : -m * sp_;
}

// Generic 1q gate under relabeling. VREG/VLANE: register/lane part of toggle v.
// UREG/ULANE: register/lane part of sign row u. hi(s) = par(lane&ULANE)^par(j&UREG).
template<int VREG, int VLANE, int UREG, int ULANE>
__device__ __forceinline__ void gate16(float (&sr)[16], float (&si)[16], int lane16,
    float g00r, float g00i, float g01r, float g01i,
    float g10r, float g10i, float g11r, float g11i)
{
    float a0r, a0i, b0r, b0i, a1r, a1i, b1r, b1i;
    if constexpr (ULANE != 0) {
        const bool lp = (__popc(lane16 & ULANE) & 1) != 0;
        a0r = lp ? g11r : g00r;  a0i = lp ? g11i : g00i;
        b0r = lp ? g10r : g01r;  b0i = lp ? g10i : g01i;
        a1r = lp ? g00r : g11r;  a1i = lp ? g00i : g11i;
        b1r = lp ? g01r : g10r;  b1i = lp ? g01i : g10i;
    } else {
        a0r = g00r; a0i = g00i; b0r = g01r; b0i = g01i;
        a1r = g11r; a1i = g11i; b1r = g10r; b1i = g10i;
    }
    constexpr bool flip = (__builtin_popcount(VREG & UREG) & 1) != 0;
    if constexpr (VLANE == 0) {
        constexpr int pivot = VREG & (-VREG);
        #pragma unroll
        for (int j = 0; j < 16; ++j) {
            if ((j & pivot) != 0) continue;
            const int j2 = j ^ VREG;
            const bool cJ = (__builtin_popcount(j & UREG) & 1) != 0;
            const bool cK = cJ ^ flip;
            const float xr = sr[j],  xi = si[j];
            const float yr = sr[j2], yi = si[j2];
            const float Ar = cJ ? a1r : a0r, Ai = cJ ? a1i : a0i;
            const float Br = cJ ? b1r : b0r, Bi = cJ ? b1i : b0i;
            const float Cr = cK ? a1r : a0r, Ci = cK ? a1i : a0i;
            const float Dr = cK ? b1r : b0r, Di = cK ? b1i : b0i;
            sr[j]  = Ar*xr - Ai*xi + Br*yr - Bi*yi;
            si[j]  = Ar*xi + Ai*xr + Br*yi + Bi*yr;
            sr[j2] = Cr*yr - Ci*yi + Dr*xr - Di*xi;
            si[j2] = Cr*yi + Ci*yr + Dr*xi + Di*xr;
        }
    } else if constexpr (VREG == 0) {
        #pragma unroll
        for (int j = 0; j < 16; ++j) {
            const float pr = __shfl_xor(sr[j], VLANE, 64);
            const float pi = __shfl_xor(si[j], VLANE, 64);
            const bool cJ = (__builtin_popcount(j & UREG) & 1) != 0;
            const float Ar = cJ ? a1r : a0r, Ai = cJ ? a1i : a0i;
            const float Br = cJ ? b1r : b0r, Bi = cJ ? b1i : b0i;
            const float xr = sr[j], xi = si[j];
            sr[j] = Ar*xr - Ai*xi + Br*pr - Bi*pi;
            si[j] = Ar*xi + Ai*xr + Br*pi + Bi*pr;
        }
    } else {
        constexpr int pivot = VREG & (-VREG);
        #pragma unroll
        for (int j = 0; j < 16; ++j) {
            if ((j & pivot) != 0) continue;
            const int j2 = j ^ VREG;
            const float p1r = __shfl_xor(sr[j2], VLANE, 64);
            const float p1i = __shfl_xor(si[j2], VLANE, 64);
            const float p2r = __shfl_xor(sr[j],  VLANE, 64);
            const float p2i = __shfl_xor(si[j],  VLANE, 64);
            const bool cJ = (__builtin_popcount(j & UREG) & 1) != 0;
            const bool cK = cJ ^ flip;
            const float xr = sr[j],  xi = si[j];
            const float yr = sr[j2], yi = si[j2];
            const float Ar = cJ ? a1r : a0r, Ai = cJ ? a1i : a0i;
            const float Br = cJ ? b1r : b0r, Bi = cJ ? b1i : b0i;
            const float Cr = cK ? a1r : a0r, Ci = cK ? a1i : a0i;
            const float Dr = cK ? b1r : b0r, Di = cK ? b1i : b0i;
            sr[j]  = Ar*xr - Ai*xi + Br*p1r - Bi*p1i;
            si[j]  = Ar*xi + Ai*xr + Br*p1i + Bi*p1r;
            sr[j2] = Cr*yr - Ci*yi + Dr*p2r - Di*p2i;
            si[j2] = Cr*yi + Ci*yr + Dr*p2i + Di*p2r;
        }
    }
}

// precomputed Rot matrix, uniform load from ws
#define ROT(L, K, VR, VL, UR, UL) do {                                  \
    const float* g_ = gates + ((L)*8 + (K))*8;                          \
    const float g0=g_[0], g1=g_[1], g2=g_[2], g3=g_[3];                 \
    const float g4=g_[4], g5=g_[5], g6=g_[6], g7=g_[7];                 \
    gate16<VR, VL, UR, UL>(sr, si, lane16, g0,g1,g2,g3,g4,g5,g6,g7);    \
} while (0)

// fused RZ(phi*0.5)*RY(theta*0.5) re-encoding (quarter-angle sincos)
#define RENC(K, VR, VL, UR, UL) do {                                    \
    float c_, s_, cp_, sp_;                                             \
    __sincosf(th[K] * 0.25f, &s_, &c_);                                 \
    __sincosf(ph[K] * 0.25f, &sp_, &cp_);                               \
    gate16<VR, VL, UR, UL>(sr, si, lane16,                              \
        c_*cp_, -c_*sp_,  -s_*cp_,  s_*sp_,                             \
        s_*cp_,  s_*sp_,   c_*cp_,  c_*sp_);                            \
} while (0)

// Rot = RZ(om)RY(th)RZ(ph): g00=c e^{-i(ph+om)/2}, g01=-s e^{+i(ph-om)/2},
// g10=s e^{-i(ph-om)/2}, g11=c e^{+i(ph+om)/2}. w is batch-independent.
__global__ __launch_bounds__(64) void prep_gates(const float* __restrict__ w,
                                                 float* __restrict__ g)
{
    const int t = threadIdx.x;
    if (t < 16) {
        const float wph = w[t*3+0], wth = w[t*3+1], wom = w[t*3+2];
        float c_, s_, ca_, sa_, cb_, sb_;
        __sincosf(wth * 0.5f, &s_, &c_);
        __sincosf(0.5f * (wph + wom), &sa_, &ca_);
        __sincosf(0.5f * (wph - wom), &sb_, &cb_);
        float* o = g + t * 8;
        o[0] =  c_*ca_;  o[1] = -c_*sa_;
        o[2] = -s_*cb_;  o[3] = -s_*sb_;
        o[4] =  s_*cb_;  o[5] = -s_*sb_;
        o[6] =  c_*ca_;  o[7] =  c_*sa_;
    }
}

__global__ __launch_bounds__(256, 2) void vqc_kernel(
    const float* __restrict__ theta,   // [B,8]
    const float* __restrict__ phi,     // [B,8]
    const float* __restrict__ jup,     // [B,28]
    const float* __restrict__ gates,   // [16,8] precomputed Rot matrices
    float* __restrict__ out,           // [B,8]
    int Btot)
{
    const int wid    = (blockIdx.x * blockDim.x + threadIdx.x) >> 6;
    const int lane   = threadIdx.x & 63;
    const int lane16 = lane & 15;
    const int bq     = wid * 4 + (lane >> 4);
    const int b      = bq < Btot ? bq : Btot - 1;   // clamp for loads

    float th[8], ph[8];
    {
        const float4* t4 = reinterpret_cast<const float4*>(theta + (size_t)b * 8);
        const float4* p4 = reinterpret_cast<const float4*>(phi   + (size_t)b * 8);
        const float4 a = t4[0], c = t4[1], d = p4[0], e = p4[1];
        th[0]=a.x; th[1]=a.y; th[2]=a.z; th[3]=a.w;
        th[4]=c.x; th[5]=c.y; th[6]=c.z; th[7]=c.w;
        ph[0]=d.x; ph[1]=d.y; ph[2]=d.z; ph[3]=d.w;
        ph[4]=e.x; ph[5]=e.y; ph[6]=e.z; ph[7]=e.w;
    }

    // ---- lane-side product over qubits 4..7 (only the selected entry) ----
    float Pr, Pi;
    {
        float er, ei;
        enc_sel(th[4], ph[4], (lane16 & 8) != 0, Pr, Pi);
        enc_sel(th[5], ph[5], (lane16 & 4) != 0, er, ei); cmul(Pr, Pi, er, ei);
        enc_sel(th[6], ph[6], (lane16 & 2) != 0, er, ei); cmul(Pr, Pi, er, ei);
        enc_sel(th[7], ph[7], (lane16 & 1) != 0, er, ei); cmul(Pr, Pi, er, ei);
    }

    // ---- register-side partial products m01 (qubits 0,1), m23 (qubits 2,3) ----
    float m01r[4], m01i[4], m23r[4], m23i[4];
    {
        float s0, c0, sp0, cp0, s1, c1, sp1, cp1;
        __sincosf(th[0]*0.5f, &s0, &c0); __sincosf(ph[0]*0.5f, &sp0, &cp0);
        __sincosf(th[1]*0.5f, &s1, &c1); __sincosf(ph[1]*0.5f, &sp1, &cp1);
        const float A0r=c0*cp0, A0i=-c0*sp0, A1r=s0*cp0, A1i=s0*sp0;
        const float B0r=c1*cp1, B0i=-c1*sp1, B1r=s1*cp1, B1i=s1*sp1;
        #pragma unroll
        for (int a = 0; a < 4; ++a) {
            float r = (a & 2) ? A1r : A0r, i = (a & 2) ? A1i : A0i;
            cmul(r, i, (a & 1) ? B1r : B0r, (a & 1) ? B1i : B0i);
            m01r[a] = r; m01i[a] = i;
        }
        __sincosf(th[2]*0.5f, &s0, &c0); __sincosf(ph[2]*0.5f, &sp0, &cp0);
        __sincosf(th[3]*0.5f, &s1, &c1); __sincosf(ph[3]*0.5f, &sp1, &cp1);
        const float C0r=c0*cp0, C0i=-c0*sp0, C1r=s0*cp0, C1i=s0*sp0;
        const float D0r=c1*cp1, D0i=-c1*sp1, D1r=s1*cp1, D1i=s1*sp1;
        #pragma unroll
        for (int a = 0; a < 4; ++a) {
            float r = (a & 2) ? C1r : C0r, i = (a & 2) ? C1i : C0i;
            cmul(r, i, (a & 1) ? D1r : D0r, (a & 1) ? D1i : D0i);
            m23r[a] = r; m23i[a] = i;
        }
    }

    // ---- IsingZZ reduction: J[28] -> c01..c23, Q0..Q3, LL ----
    float c01, c02, c03, c12, c13, c23, Q0, Q1, Q2, Q3, LL;
    {
        const float4* J4 = reinterpret_cast<const float4*>(jup + (size_t)b * 28);
        const float z4 = (lane16 & 8) ? -1.f : 1.f;
        const float z5 = (lane16 & 4) ? -1.f : 1.f;
        const float z6 = (lane16 & 2) ? -1.f : 1.f;
        const float z7 = (lane16 & 1) ? -1.f : 1.f;
        const float4 x0 = J4[0];   // J0..J3
        const float4 x1 = J4[1];   // J4..J7
        const float4 x2 = J4[2];   // J8..J11
        const float4 x3 = J4[3];   // J12..J15
        const float4 x4 = J4[4];   // J16..J19
        const float4 x5 = J4[5];   // J20..J23
        const float4 x6 = J4[6];   // J24..J27
        c01 = x0.x; c02 = x0.y; c03 = x0.z;
        Q0  = x0.w*z4 + x1.x*z5 + x1.y*z6 + x1.z*z7;
        c12 = x1.w; c13 = x2.x;
        Q1  = x2.y*z4 + x2.z*z5 + x2.w*z6 + x3.x*z7;
        c23 = x3.y;
        Q2  = x3.z*z4 + x3.w*z5 + x4.x*z6 + x4.y*z7;
        Q3  = x4.z*z4 + x4.w*z5 + x5.x*z6 + x5.y*z7;
        LL  = x5.z*(z4*z5) + x5.w*(z4*z6) + x6.x*(z4*z7)
            + x6.y*(z5*z6) + x6.z*(z5*z7) + x6.w*(z6*z7);
    }

    // ---- init amplitudes: product state x Ising phase ----
    float sr[16], si[16];
    constexpr float HPI = 1.5707963267948966f;
    #pragma unroll
    for (int j = 0; j < 16; ++j) {
        float ur = m01r[j >> 2], ui = m01i[j >> 2];
        cmul(ur, ui, m23r[j & 3], m23i[j & 3]);
        cmul(ur, ui, Pr, Pi);
        float S = LL;
        S += ((__builtin_popcount(j & 0xC) & 1) ? -c01 : c01);
        S += ((__builtin_popcount(j & 0xA) & 1) ? -c02 : c02);
        S += ((__builtin_popcount(j & 0x9) & 1) ? -c03 : c03);
        S += ((__builtin_popcount(j & 0x6) & 1) ? -c12 : c12);
        S += ((__builtin_popcount(j & 0x5) & 1) ? -c13 : c13);
        S += ((__builtin_popcount(j & 0x3) & 1) ? -c23 : c23);
        S += ((j & 8) ? -Q0 : Q0);
        S += ((j & 4) ? -Q1 : Q1);
        S += ((j & 2) ? -Q2 : Q2);
        S += ((j & 1) ? -Q3 : Q3);
        float se, ce;
        __sincosf(-HPI * S, &se, &ce);
        sr[j] = ur * ce - ui * se;
        si[j] = ur * se + ui * ce;
    }

    // ---- layer-0 Rot gates (A = I): v = u = e_p, p = 7-k ----
    ROT(0, 0, 0x8, 0x0, 0x8, 0x0);
    ROT(0, 1, 0x4, 0x0, 0x4, 0x0);
    ROT(0, 2, 0x2, 0x0, 0x2, 0x0);
    ROT(0, 3, 0x1, 0x0, 0x1, 0x0);
    ROT(0, 4, 0x0, 0x8, 0x0, 0x8);
    ROT(0, 5, 0x0, 0x4, 0x0, 0x4);
    ROT(0, 6, 0x0, 0x2, 0x0, 0x2);
    ROT(0, 7, 0x0, 0x1, 0x0, 0x1);

    // layer-0 CNOT ring folded into relabeling (v,u tables verified in R2)
    RENC(0, 0xC, 0x0, 0x7, 0xF);
    RENC(1, 0x6, 0x0, 0xC, 0x0);
    RENC(2, 0x3, 0x0, 0xE, 0x0);
    RENC(3, 0x1, 0x8, 0xF, 0x0);
    RENC(4, 0x0, 0xC, 0xF, 0x8);
    RENC(5, 0x0, 0x6, 0xF, 0xC);
    RENC(6, 0x0, 0x3, 0xF, 0xE);
    RENC(7, 0xC, 0x1, 0xF, 0xF);

    ROT(1, 0, 0xC, 0x0, 0x7, 0xF);
    ROT(1, 1, 0x6, 0x0, 0xC, 0x0);
    ROT(1, 2, 0x3, 0x0, 0xE, 0x0);
    ROT(1, 3, 0x1, 0x8, 0xF, 0x0);
    ROT(1, 4, 0x0, 0xC, 0xF, 0x8);
    ROT(1, 5, 0x0, 0x6, 0xF, 0xC);
    ROT(1, 6, 0x0, 0x3, 0xF, 0xE);
    ROT(1, 7, 0xC, 0x1, 0xF, 0xF);

    // ---- readout: probs, 16-point WHT over register index, lane signs ----
    float p[16];
    #pragma unroll
    for (int j = 0; j < 16; ++j) p[j] = sr[j]*sr[j] + si[j]*si[j];
    #pragma unroll
    for (int st = 1; st < 16; st <<= 1) {
        #pragma unroll
        for (int j = 0; j < 16; ++j) {
            if ((j & st) != 0) continue;
            const float a = p[j], bb = p[j | st];
            p[j] = a + bb;  p[j | st] = a - bb;
        }
    }
    float o[8];
    o[0] = (__popc(lane16 & 0x6) & 1) ? -p[0xE] : p[0xE];
    o[1] = (__popc(lane16 & 0x3) & 1) ? -p[0xF] : p[0xF];
    o[2] = (__popc(lane16 & 0xF) & 1) ? -p[0x9] : p[0x9];
    o[3] = p[0x3];
    o[4] = (__popc(lane16 & 0x7) & 1) ? -p[0x6] : p[0x6];
    o[5] = (__popc(lane16 & 0xC) & 1) ? -p[0xC] : p[0xC];
    o[6] = (__popc(lane16 & 0x9) & 1) ? -p[0x9] : p[0x9];
    o[7] = (__popc(lane16 & 0x3) & 1) ? -p[0x3] : p[0x3];

    #pragma unroll
    for (int m = 1; m <= 8; m <<= 1) {
        #pragma unroll
        for (int q = 0; q < 8; ++q) o[q] += __shfl_xor(o[q], m, 64);
    }

    if (lane16 == 0 && bq < Btot) {
        float4* op = reinterpret_cast<float4*>(out + (size_t)bq * 8);
        op[0] = make_float4(o[0], o[1], o[2], o[3]);
        op[1] = make_float4(o[4], o[5], o[6], o[7]);
    }
}

extern "C" void kernel_launch(void* const* d_in, const int* in_sizes, int n_in,
                              void* d_out, int out_size, void* d_ws, size_t ws_size,
                              hipStream_t stream) {
    const float* theta = (const float*)d_in[0];
    const float* phi   = (const float*)d_in[1];
    const float* jup   = (const float*)d_in[2];
    const float* w     = (const float*)d_in[3];
    float* out   = (float*)d_out;
    float* gates = (float*)d_ws;                 // 16 gates x 8 floats = 512 B

    const int B = in_sizes[0] / 8;               // 16384
    hipLaunchKernelGGL(prep_gates, dim3(1), dim3(64), 0, stream, w, gates);

    const int threads = 256;                     // 4 waves, 16 batch elems / block
    const int blocks = (B + 15) / 16;            // 1024
    hipLaunchKernelGGL(vqc_kernel, dim3(blocks), dim3(threads), 0, stream,
                       theta, phi, jup, gates, out, B);
}

// Round 4
// 82.471 us; speedup vs baseline: 1.7669x; 1.3270x over previous
//
#include <hip/hip_runtime.h>

// TorchVQC: 8-qubit statevector, B=16384, D=256, fp32 complex.
// Layout: 4 batch elements per wave (16 lanes each), 16 amplitudes per lane.
// Stored index s = (j<<4) | lane16 : lane16 = s[3:0], register j = s[7:4].
// CNOTs folded away via GF(2) relabeling (v/u tables verified R2/R3).
// R4: (a) fuse RENC(k) with ROT(1,k) (same true qubit, commuting neighbors)
//     (b) float2 packed complex math -> v_pk_fma_f32 (VOP3P op_sel folds
//         the splat/neg/swap), halving gate-core instruction count
//     (c) 64-thread blocks for finer tail scheduling.

using f2 = __attribute__((ext_vector_type(2))) float;  // (re, im)

__device__ __forceinline__ f2 pkfma(f2 a, f2 b, f2 c) {
#if __has_builtin(__builtin_elementwise_fma)
    return __builtin_elementwise_fma(a, b, c);
#else
    f2 r; r.x = fmaf(a.x, b.x, c.x); r.y = fmaf(a.y, b.y, c.y); return r;
#endif
}

// w*z (complex): (wr,wr)*z + (-wi,wi)*swap(z)
__device__ __forceinline__ f2 cmul2(f2 w, f2 z) {
    const f2 wr = (f2){w.x, w.x};
    const f2 wi = (f2){-w.y, w.y};
    const f2 zs = (f2){z.y, z.x};
    return pkfma(wi, zs, wr * z);
}
// acc + w*z
__device__ __forceinline__ f2 cmadd(f2 acc, f2 w, f2 z) {
    const f2 wr = (f2){w.x, w.x};
    const f2 wi = (f2){-w.y, w.y};
    const f2 zs = (f2){z.y, z.x};
    return pkfma(wi, zs, pkfma(wr, z, acc));
}

__device__ __forceinline__ f2 shflx(f2 v, int m) {
    f2 r; r.x = __shfl_xor(v.x, m, 64); r.y = __shfl_xor(v.y, m, 64); return r;
}

// selected encoding-column entry: hi ? (s*cp, s*sp) : (c*cp, -c*sp)
__device__ __forceinline__ f2 enc_sel(float t, float p, bool hi) {
    float s_, c_, sp_, cp_;
    __sincosf(t * 0.5f, &s_, &c_);
    __sincosf(p * 0.5f, &sp_, &cp_);
    const float m = hi ? s_ : c_;
    f2 r; r.x = m * cp_; r.y = hi ? m * sp_ : -m * sp_;
    return r;
}

// Generic 1q gate under relabeling. VREG/VLANE: register/lane part of toggle v.
// UREG/ULANE: register/lane part of sign row u. hi(s) = par(lane&ULANE)^par(j&UREG).
template<int VREG, int VLANE, int UREG, int ULANE>
__device__ __forceinline__ void gate16(f2 (&s)[16], int lane16,
                                       f2 g00, f2 g01, f2 g10, f2 g11)
{
    f2 a0, b0, a1, b1;
    if constexpr (ULANE != 0) {
        const bool lp = (__popc(lane16 & ULANE) & 1) != 0;
        a0 = lp ? g11 : g00;  b0 = lp ? g10 : g01;
        a1 = lp ? g00 : g11;  b1 = lp ? g01 : g10;
    } else {
        a0 = g00; b0 = g01; a1 = g11; b1 = g10;
    }
    constexpr bool flip = (__builtin_popcount(VREG & UREG) & 1) != 0;
    if constexpr (VLANE == 0) {
        constexpr int pivot = VREG & (-VREG);
        #pragma unroll
        for (int j = 0; j < 16; ++j) {
            if ((j & pivot) != 0) continue;
            const int j2 = j ^ VREG;
            const bool cJ = (__builtin_popcount(j & UREG) & 1) != 0;
            const bool cK = cJ ^ flip;
            const f2 x = s[j], y = s[j2];
            const f2 A = cJ ? a1 : a0, B = cJ ? b1 : b0;
            const f2 C = cK ? a1 : a0, D = cK ? b1 : b0;
            s[j]  = cmadd(cmul2(A, x), B, y);
            s[j2] = cmadd(cmul2(C, y), D, x);
        }
    } else if constexpr (VREG == 0) {
        #pragma unroll
        for (int j = 0; j < 16; ++j) {
            const f2 p = shflx(s[j], VLANE);
            const bool cJ = (__builtin_popcount(j & UREG) & 1) != 0;
            const f2 A = cJ ? a1 : a0, B = cJ ? b1 : b0;
            s[j] = cmadd(cmul2(A, s[j]), B, p);
        }
    } else {
        constexpr int pivot = VREG & (-VREG);
        #pragma unroll
        for (int j = 0; j < 16; ++j) {
            if ((j & pivot) != 0) continue;
            const int j2 = j ^ VREG;
            const f2 p1 = shflx(s[j2], VLANE);
            const f2 p2 = shflx(s[j],  VLANE);
            const bool cJ = (__builtin_popcount(j & UREG) & 1) != 0;
            const bool cK = cJ ^ flip;
            const f2 A = cJ ? a1 : a0, B = cJ ? b1 : b0;
            const f2 C = cK ? a1 : a0, D = cK ? b1 : b0;
            s[j]  = cmadd(cmul2(A, s[j]),  B, p1);
            s[j2] = cmadd(cmul2(C, s[j2]), D, p2);
        }
    }
}

// layer-0 Rot: precomputed matrix, uniform load from ws
#define ROT0(K, VR, VL, UR, UL) do {                                    \
    const float* g_ = gates + (K)*8;                                    \
    const f2 R00={g_[0],g_[1]}, R01={g_[2],g_[3]};                      \
    const f2 R10={g_[4],g_[5]}, R11={g_[6],g_[7]};                      \
    gate16<VR, VL, UR, UL>(s, lane16, R00, R01, R10, R11);              \
} while (0)

// fused: F = Rot(1,K) . Renc(K)   (Renc = RZ(ph/2) RY(th/2), quarter angles)
#define FUSED(K, VR, VL, UR, UL) do {                                   \
    const float* g_ = gates + (8 + (K))*8;                              \
    const f2 R00={g_[0],g_[1]}, R01={g_[2],g_[3]};                      \
    const f2 R10={g_[4],g_[5]}, R11={g_[6],g_[7]};                      \
    float c_, s_, cp_, sp_;                                             \
    __sincosf(th[K] * 0.25f, &s_, &c_);                                 \
    __sincosf(ph[K] * 0.25f, &sp_, &cp_);                               \
    const f2 E00={ c_*cp_, -c_*sp_}, E01={-s_*cp_,  s_*sp_};            \
    const f2 E10={ s_*cp_,  s_*sp_}, E11={ c_*cp_,  c_*sp_};            \
    const f2 F00 = cmadd(cmul2(R00, E00), R01, E10);                    \
    const f2 F01 = cmadd(cmul2(R00, E01), R01, E11);                    \
    const f2 F10 = cmadd(cmul2(R10, E00), R11, E10);                    \
    const f2 F11 = cmadd(cmul2(R10, E01), R11, E11);                    \
    gate16<VR, VL, UR, UL>(s, lane16, F00, F01, F10, F11);              \
} while (0)

// Rot = RZ(om)RY(th)RZ(ph): g00=c e^{-i(ph+om)/2}, g01=-s e^{+i(ph-om)/2},
// g10=s e^{-i(ph-om)/2}, g11=c e^{+i(ph+om)/2}. w is batch-independent.
__global__ __launch_bounds__(64) void prep_gates(const float* __restrict__ w,
                                                 float* __restrict__ g)
{
    const int t = threadIdx.x;
    if (t < 16) {
        const float wph = w[t*3+0], wth = w[t*3+1], wom = w[t*3+2];
        float c_, s_, ca_, sa_, cb_, sb_;
        __sincosf(wth * 0.5f, &s_, &c_);
        __sincosf(0.5f * (wph + wom), &sa_, &ca_);
        __sincosf(0.5f * (wph - wom), &sb_, &cb_);
        float* o = g + t * 8;
        o[0] =  c_*ca_;  o[1] = -c_*sa_;
        o[2] = -s_*cb_;  o[3] = -s_*sb_;
        o[4] =  s_*cb_;  o[5] = -s_*sb_;
        o[6] =  c_*ca_;  o[7] =  c_*sa_;
    }
}

__global__ __launch_bounds__(64, 4) void vqc_kernel(
    const float* __restrict__ theta,   // [B,8]
    const float* __restrict__ phi,     // [B,8]
    const float* __restrict__ jup,     // [B,28]
    const float* __restrict__ gates,   // [16,8] precomputed Rot matrices
    float* __restrict__ out,           // [B,8]
    int Btot)
{
    const int wid    = blockIdx.x;         // one wave per block
    const int lane   = threadIdx.x & 63;
    const int lane16 = lane & 15;
    const int bq     = wid * 4 + (lane >> 4);
    const int b      = bq < Btot ? bq : Btot - 1;   // clamp for loads

    float th[8], ph[8];
    {
        const float4* t4 = reinterpret_cast<const float4*>(theta + (size_t)b * 8);
        const float4* p4 = reinterpret_cast<const float4*>(phi   + (size_t)b * 8);
        const float4 a = t4[0], c = t4[1], d = p4[0], e = p4[1];
        th[0]=a.x; th[1]=a.y; th[2]=a.z; th[3]=a.w;
        th[4]=c.x; th[5]=c.y; th[6]=c.z; th[7]=c.w;
        ph[0]=d.x; ph[1]=d.y; ph[2]=d.z; ph[3]=d.w;
        ph[4]=e.x; ph[5]=e.y; ph[6]=e.z; ph[7]=e.w;
    }

    // ---- lane-side encoding product over qubits 4..7 ----
    f2 P = enc_sel(th[4], ph[4], (lane16 & 8) != 0);
    P = cmul2(P, enc_sel(th[5], ph[5], (lane16 & 4) != 0));
    P = cmul2(P, enc_sel(th[6], ph[6], (lane16 & 2) != 0));
    P = cmul2(P, enc_sel(th[7], ph[7], (lane16 & 1) != 0));

    // ---- register-side partial products m01 (qubits 0,1), m23 (qubits 2,3) ----
    f2 m01[4], m23[4];
    {
        float s0, c0, sp0, cp0, s1, c1, sp1, cp1;
        __sincosf(th[0]*0.5f, &s0, &c0); __sincosf(ph[0]*0.5f, &sp0, &cp0);
        __sincosf(th[1]*0.5f, &s1, &c1); __sincosf(ph[1]*0.5f, &sp1, &cp1);
        const f2 A0={c0*cp0,-c0*sp0}, A1={s0*cp0,s0*sp0};
        const f2 B0={c1*cp1,-c1*sp1}, B1={s1*cp1,s1*sp1};
        #pragma unroll
        for (int a = 0; a < 4; ++a)
            m01[a] = cmul2((a & 2) ? A1 : A0, (a & 1) ? B1 : B0);
        __sincosf(th[2]*0.5f, &s0, &c0); __sincosf(ph[2]*0.5f, &sp0, &cp0);
        __sincosf(th[3]*0.5f, &s1, &c1); __sincosf(ph[3]*0.5f, &sp1, &cp1);
        const f2 C0={c0*cp0,-c0*sp0}, C1={s0*cp0,s0*sp0};
        const f2 D0={c1*cp1,-c1*sp1}, D1={s1*cp1,s1*sp1};
        #pragma unroll
        for (int a = 0; a < 4; ++a)
            m23[a] = cmul2((a & 2) ? C1 : C0, (a & 1) ? D1 : D0);
    }

    // ---- IsingZZ reduction: J[28] -> c01..c23, Q0..Q3, LL ----
    float c01, c02, c03, c12, c13, c23, Q0, Q1, Q2, Q3, LL;
    {
        const float4* J4 = reinterpret_cast<const float4*>(jup + (size_t)b * 28);
        const float z4 = (lane16 & 8) ? -1.f : 1.f;
        const float z5 = (lane16 & 4) ? -1.f : 1.f;
        const float z6 = (lane16 & 2) ? -1.f : 1.f;
        const float z7 = (lane16 & 1) ? -1.f : 1.f;
        const float4 x0 = J4[0], x1 = J4[1], x2 = J4[2], x3 = J4[3];
        const float4 x4 = J4[4], x5 = J4[5], x6 = J4[6];
        c01 = x0.x; c02 = x0.y; c03 = x0.z;
        Q0  = x0.w*z4 + x1.x*z5 + x1.y*z6 + x1.z*z7;
        c12 = x1.w; c13 = x2.x;
        Q1  = x2.y*z4 + x2.z*z5 + x2.w*z6 + x3.x*z7;
        c23 = x3.y;
        Q2  = x3.z*z4 + x3.w*z5 + x4.x*z6 + x4.y*z7;
        Q3  = x4.z*z4 + x4.w*z5 + x5.x*z6 + x5.y*z7;
        LL  = x5.z*(z4*z5) + x5.w*(z4*z6) + x6.x*(z4*z7)
            + x6.y*(z5*z6) + x6.z*(z5*z7) + x6.w*(z6*z7);
    }

    // ---- init amplitudes: product state x Ising phase ----
    f2 s[16];
    constexpr float HPI = 1.5707963267948966f;
    #pragma unroll
    for (int j = 0; j < 16; ++j) {
        f2 u = cmul2(cmul2(m01[j >> 2], m23[j & 3]), P);
        float S = LL;
        S += ((__builtin_popcount(j & 0xC) & 1) ? -c01 : c01);
        S += ((__builtin_popcount(j & 0xA) & 1) ? -c02 : c02);
        S += ((__builtin_popcount(j & 0x9) & 1) ? -c03 : c03);
        S += ((__builtin_popcount(j & 0x6) & 1) ? -c12 : c12);
        S += ((__builtin_popcount(j & 0x5) & 1) ? -c13 : c13);
        S += ((__builtin_popcount(j & 0x3) & 1) ? -c23 : c23);
        S += ((j & 8) ? -Q0 : Q0);
        S += ((j & 4) ? -Q1 : Q1);
        S += ((j & 2) ? -Q2 : Q2);
        S += ((j & 1) ? -Q3 : Q3);
        float se, ce;
        __sincosf(-HPI * S, &se, &ce);
        s[j] = cmul2(u, (f2){ce, se});
    }

    // ---- layer-0 Rot gates (A = I): v = u = e_p, p = 7-k ----
    ROT0(0, 0x8, 0x0, 0x8, 0x0);
    ROT0(1, 0x4, 0x0, 0x4, 0x0);
    ROT0(2, 0x2, 0x0, 0x2, 0x0);
    ROT0(3, 0x1, 0x0, 0x1, 0x0);
    ROT0(4, 0x0, 0x8, 0x0, 0x8);
    ROT0(5, 0x0, 0x4, 0x0, 0x4);
    ROT0(6, 0x0, 0x2, 0x0, 0x2);
    ROT0(7, 0x0, 0x1, 0x0, 0x1);

    // ---- layer-0 CNOT ring folded into relabeling; RENC(k)+ROT(1,k) fused
    //      (same true qubit, neighbors commute) ----
    FUSED(0, 0xC, 0x0, 0x7, 0xF);
    FUSED(1, 0x6, 0x0, 0xC, 0x0);
    FUSED(2, 0x3, 0x0, 0xE, 0x0);
    FUSED(3, 0x1, 0x8, 0xF, 0x0);
    FUSED(4, 0x0, 0xC, 0xF, 0x8);
    FUSED(5, 0x0, 0x6, 0xF, 0xC);
    FUSED(6, 0x0, 0x3, 0xF, 0xE);
    FUSED(7, 0xC, 0x1, 0xF, 0xF);

    // layer-1 CNOT ring folded into readout signs (final A rows, verified R2)
    // ---- readout: probs, 16-point WHT over register index, lane signs ----
    float p[16];
    #pragma unroll
    for (int j = 0; j < 16; ++j) p[j] = s[j].x*s[j].x + s[j].y*s[j].y;
    #pragma unroll
    for (int st = 1; st < 16; st <<= 1) {
        #pragma unroll
        for (int j = 0; j < 16; ++j) {
            if ((j & st) != 0) continue;
            const float a = p[j], bb = p[j | st];
            p[j] = a + bb;  p[j | st] = a - bb;
        }
    }
    float o[8];
    o[0] = (__popc(lane16 & 0x6) & 1) ? -p[0xE] : p[0xE];
    o[1] = (__popc(lane16 & 0x3) & 1) ? -p[0xF] : p[0xF];
    o[2] = (__popc(lane16 & 0xF) & 1) ? -p[0x9] : p[0x9];
    o[3] = p[0x3];
    o[4] = (__popc(lane16 & 0x7) & 1) ? -p[0x6] : p[0x6];
    o[5] = (__popc(lane16 & 0xC) & 1) ? -p[0xC] : p[0xC];
    o[6] = (__popc(lane16 & 0x9) & 1) ? -p[0x9] : p[0x9];
    o[7] = (__popc(lane16 & 0x3) & 1) ? -p[0x3] : p[0x3];

    #pragma unroll
    for (int m = 1; m <= 8; m <<= 1) {
        #pragma unroll
        for (int q = 0; q < 8; ++q) o[q] += __shfl_xor(o[q], m, 64);
    }

    if (lane16 == 0 && bq < Btot) {
        float4* op = reinterpret_cast<float4*>(out + (size_t)bq * 8);
        op[0] = make_float4(o[0], o[1], o[2], o[3]);
        op[1] = make_float4(o[4], o[5], o[6], o[7]);
    }
}

extern "C" void kernel_launch(void* const* d_in, const int* in_sizes, int n_in,
                              void* d_out, int out_size, void* d_ws, size_t ws_size,
                              hipStream_t stream) {
    const float* theta = (const float*)d_in[0];
    const float* phi   = (const float*)d_in[1];
    const float* jup   = (const float*)d_in[2];
    const float* w     = (const float*)d_in[3];
    float* out   = (float*)d_out;
    float* gates = (float*)d_ws;                 // 16 gates x 8 floats = 512 B

    const int B = in_sizes[0] / 8;               // 16384
    hipLaunchKernelGGL(prep_gates, dim3(1), dim3(64), 0, stream, w, gates);

    const int blocks = (B + 3) / 4;              // 4096: one wave / block
    hipLaunchKernelGGL(vqc_kernel, dim3(blocks), dim3(64), 0, stream,
                       theta, phi, jup, gates, out, B);
}